// Round 5
// baseline (165.985 us; speedup 1.0000x reference)
//
#include <hip/hip_runtime.h>
#include <stdint.h>

#define KK 5
#define BS 8
#define NCH 64          // T/BS chunks
#define ROWF 40         // floats per (batch,chunk) row: 8 steps x 5
#define PITCH 42        // LDS row pitch in words (42 mod 32 = 10 -> 2-way alias, free)
#define DPITCH 516      // decode-staging row bytes (129 words, conflict-free-ish)

struct Stage { float4 v[10]; };   // one chunk: 640 float4 over 64 lanes = 10/lane
struct TBlk { int4 lo, hi; };     // 8 tags

__device__ __forceinline__ int telt(const TBlk& tb, int s) {  // s compile-time
  const int4 v = (s < 4) ? tb.lo : tb.hi;
  const int m = s & 3;
  return m == 0 ? v.x : (m == 1 ? v.y : (m == 2 ? v.z : v.w));
}
// runtime ct in 0..4 over 5 statically-indexed floats -> 4 cndmask
__device__ __forceinline__ float sel5(float v0, float v1, float v2, float v3,
                                      float v4, int ct) {
  float u = v0;
  u = (ct == 1) ? v1 : u;
  u = (ct == 2) ? v2 : u;
  u = (ct == 3) ? v3 : u;
  u = (ct == 4) ? v4 : u;
  return u;
}

// issue the 10 coalesced-ish float4 loads for chunk t0/8 (no waits)
__device__ __forceinline__ void stage_load(Stage& S, const float* __restrict__ pot,
                                           int bbase, int TK, int t0, int lane) {
#pragma unroll
  for (int j = 0; j < 10; ++j) {
    const int g = lane + 64 * j;          // 0..639
    const int row = g / 10, col = g % 10; // magic-div by compiler
    S.v[j] = *(const float4*)(pot + (size_t)(bbase + row) * TK + t0 * KK + col * 4);
  }
}
// write staged regs into one LDS buffer (compiler inserts the vmcnt wait)
__device__ __forceinline__ void stage_flush(const Stage& S, float* __restrict__ buf,
                                            int lane) {
#pragma unroll
  for (int j = 0; j < 10; ++j) {
    const int g = lane + 64 * j;
    const int row = g / 10, col = g % 10;
    float* d = buf + row * PITCH + col * 4;   // 8B-aligned -> 2x ds_write_b64
    d[0] = S.v[j].x; d[1] = S.v[j].y; d[2] = S.v[j].z; d[3] = S.v[j].w;
  }
}

// ---------------- Viterbi: one 8-step chunk from cv[40] ----------------
__device__ __forceinline__ void vit_chunk(const float (&cv)[ROWF], int blk, int len,
                                          const float (&tr)[KK][KK], float (&a)[KK],
                                          uint4* __restrict__ bp4, int b) {
  uint32_t w[4] = {0u, 0u, 0u, 0u};
#pragma unroll
  for (int s = 0; s < BS; ++s) {
    const int t = blk * BS + s;
    if (s == 0 && blk == 0) {
#pragma unroll
      for (int j = 0; j < KK; ++j) a[j] = cv[j];
    } else {
      const bool act = (t < len);
      float nv[KK];
      uint32_t bits = 0;
#pragma unroll
      for (int j = 0; j < KK; ++j) {
        const float s0 = a[0] + tr[0][j];
        const float s1 = a[1] + tr[1][j];
        const float s2 = a[2] + tr[2][j];
        const float s3 = a[3] + tr[3][j];
        const float s4 = a[4] + tr[4][j];
        const float bm = fmaxf(fmaxf(fmaxf(s0, s1), fmaxf(s2, s3)), s4);
        int bi = 4;                     // first-max tie-break == jnp.argmax
        bi = (s3 == bm) ? 3 : bi;
        bi = (s2 == bm) ? 2 : bi;
        bi = (s1 == bm) ? 1 : bi;
        bi = (s0 == bm) ? 0 : bi;
        nv[j] = bm + cv[s * KK + j];
        bits |= (uint32_t)bi << (3 * j);
      }
      if (act) {
#pragma unroll
        for (int j = 0; j < KK; ++j) a[j] = nv[j];
        w[s >> 1] |= bits << ((s & 1) << 4);
      }
    }
  }
  if (blk * BS < len) bp4[(size_t)b * NCH + blk] = make_uint4(w[0], w[1], w[2], w[3]);
}

// ---------------- forward + score: one 8-step chunk ----------------
__device__ __forceinline__ void fwd_chunk(const float (&cv)[ROWF], const TBlk& TB,
                                          int blk, int len, const float (&W)[KK][KK],
                                          const float* __restrict__ s_trans,
                                          float (&p)[KK], float& Cacc,
                                          float& unary, float& binary, int& pt) {
#pragma unroll
  for (int s = 0; s < BS; ++s) {
    const int t = blk * BS + s;
    if (s == 0 && blk == 0) {
#pragma unroll
      for (int j = 0; j < KK; ++j) p[j] = __expf(cv[j]);
      pt = telt(TB, 0);
      unary = sel5(cv[0], cv[1], cv[2], cv[3], cv[4], pt);
    } else {
      const bool act = (t < len);
      float E[KK], np_[KK];
#pragma unroll
      for (int j = 0; j < KK; ++j) E[j] = __expf(cv[s * KK + j]);
#pragma unroll
      for (int j = 0; j < KK; ++j) {
        float acc = p[0] * W[0][j];
        acc = fmaf(p[1], W[1][j], acc);
        acc = fmaf(p[2], W[2][j], acc);
        acc = fmaf(p[3], W[3][j], acc);
        acc = fmaf(p[4], W[4][j], acc);
        np_[j] = acc * E[j];
      }
      const int ct = telt(TB, s);
      const float u = sel5(cv[s * KK], cv[s * KK + 1], cv[s * KK + 2],
                           cv[s * KK + 3], cv[s * KK + 4], ct);
      const float bnr = s_trans[pt * KK + ct];
      if (act) {
#pragma unroll
        for (int j = 0; j < KK; ++j) p[j] = np_[j];
        unary += u;
        binary += bnr;
        pt = ct;
      }
    }
  }
  // renorm once per chunk (representation-neutral; safe for frozen lanes)
  const float m = fmaxf(fmaxf(fmaxf(p[0], p[1]), fmaxf(p[2], p[3])), p[4]);
  const float r = 1.0f / m;
#pragma unroll
  for (int j = 0; j < KK; ++j) p[j] *= r;
  Cacc += __logf(m);
}

// ---------------------------------------------------------------------------
// 256 blocks x 64 threads, ONE wave per block (no barriers anywhere -> all
// prefetch stays in flight). Thread-per-batch compute (pure-VALU chain).
// Blocks g (Viterbi) and g+128 (forward+score) cover the same 64 batches and
// land on the same XCD (128 % 8 == 0) for pot L2 reuse.
// Per chunk: coalesced global->reg stage, reg->LDS transpose, per-thread LDS
// row reads. LDS double-buffered; stage for chunk k+2 issued during chunk k.
// ---------------------------------------------------------------------------
__launch_bounds__(64)
__global__ void crf_kernel(const float* __restrict__ pot,
                           const float* __restrict__ trans,
                           const int* __restrict__ lens,
                           const int* __restrict__ tags,
                           float* __restrict__ out,
                           uint4* __restrict__ bp4,
                           int B, int T) {
  __shared__ float sbuf[2][64 * PITCH];     // 21 KB staging, double-buffered
  __shared__ uint8_t s_dec[64 * DPITCH];    // 33 KB decode staging (V only)
  __shared__ float s_trans[KK * KK];
  const int lane = threadIdx.x;
  const int ngrp = B / 64;                  // 128
  const int role = (blockIdx.x >= ngrp) ? 1 : 0;
  const int grp = blockIdx.x - role * ngrp;
  const int bbase = grp * 64;
  const int b = bbase + lane;
  const int len = lens[b];
  const int TK = T * KK;                    // 2560

  if (lane < KK * KK) s_trans[lane] = trans[lane];

  int ml = len;
#pragma unroll
  for (int d = 1; d < 64; d <<= 1) ml = max(ml, __shfl_xor(ml, d));
  const int nblk = (ml + BS - 1) / BS;      // wave-uniform

  // ---- staging pipeline prologue ----
  Stage S;
  stage_load(S, pot, bbase, TK, 0, lane);
  stage_flush(S, sbuf[0], lane);
  stage_load(S, pot, bbase, TK, BS * min(1, nblk - 1), lane);

  if (role == 0) {
    // ========================= Viterbi =========================
    float tr[KK][KK];
#pragma unroll
    for (int i = 0; i < KK; ++i)
#pragma unroll
      for (int j = 0; j < KK; ++j) tr[i][j] = trans[i * KK + j];  // uniform s_loads
    float a[KK];
    for (int k = 0; k < nblk; ++k) {
      const float* ldsrow = &sbuf[k & 1][lane * PITCH];
      float cv[ROWF];
#pragma unroll
      for (int i = 0; i < ROWF; ++i) cv[i] = ldsrow[i];
      if (k + 1 < nblk) {
        stage_flush(S, sbuf[(k + 1) & 1], lane);
        stage_load(S, pot, bbase, TK, BS * min(k + 2, nblk - 1), lane);
      }
      vit_chunk(cv, k, len, tr, a, bp4, b);
    }
    // final alpha argmax (first-max)
    const float bm = fmaxf(fmaxf(fmaxf(a[0], a[1]), fmaxf(a[2], a[3])), a[4]);
    int last = 4;
    last = (a[3] == bm) ? 3 : last;
    last = (a[2] == bm) ? 2 : last;
    last = (a[1] == bm) ? 1 : last;
    last = (a[0] == bm) ? 0 : last;

    // ========== backtrace: 6-deep prefetch ring over bp chunks ==========
    s_dec[lane * DPITCH + (len - 1)] = (uint8_t)last;
    int tag = last;
    const uint4* __restrict__ bq = bp4 + (size_t)b * NCH;
    int i = nblk - 1;
    uint4 v0 = bq[i];
    uint4 v1 = bq[max(i - 1, 0)];
    uint4 v2 = bq[max(i - 2, 0)];
    uint4 v3 = bq[max(i - 3, 0)];
    uint4 v4 = bq[max(i - 4, 0)];
    uint4 v5 = bq[max(i - 5, 0)];
    while (i >= 0) {
      const int t8 = i * BS;
#pragma unroll
      for (int s = BS - 1; s >= 0; --s) {
        const int t = t8 + s;
        if (t >= 1 && t < len) {
          const uint32_t w = (s >> 1) == 0 ? v0.x : (s >> 1) == 1 ? v0.y
                           : (s >> 1) == 2 ? v0.z : v0.w;
          const int pv = (int)((w >> ((3 * tag) + ((s & 1) << 4))) & 7u);
          s_dec[lane * DPITCH + (t - 1)] = (uint8_t)pv;
          tag = pv;
        }
      }
      v0 = v1; v1 = v2; v2 = v3; v3 = v4; v4 = v5;
      v5 = bq[max(i - 6, 0)];
      --i;
    }
    // ============== coalesced decode flush: LDS u8 -> f32 rows ==============
    for (int r = 0; r < 64; ++r) {
      const int lr = __shfl(len, r);
      const uint8_t* rowp = s_dec + r * DPITCH + lane * 8;
      const uint32_t w0 = *(const uint32_t*)(rowp);
      const uint32_t w1 = *(const uint32_t*)(rowp + 4);
      const int t0 = lane * 8;
      float f[8];
#pragma unroll
      for (int q = 0; q < 8; ++q) {
        const uint32_t byte = ((q < 4 ? w0 >> (8 * q) : w1 >> (8 * (q - 4))) & 0xffu);
        f[q] = (t0 + q < lr) ? (float)byte : 0.0f;
      }
      float* orow = out + (size_t)(bbase + r) * T + t0;
      *(float4*)(orow)     = make_float4(f[0], f[1], f[2], f[3]);
      *(float4*)(orow + 4) = make_float4(f[4], f[5], f[6], f[7]);
    }

  } else {
    // ==================== forward (linear-space) + score ====================
    float W[KK][KK];
#pragma unroll
    for (int i = 0; i < KK; ++i)
#pragma unroll
      for (int j = 0; j < KK; ++j) W[i][j] = __expf(trans[i * KK + j]);
    float p[KK];
    float Cacc = 0.0f, unary = 0.0f, binary = 0.0f;
    int pt = 0;
    const int* __restrict__ tg = tags + (size_t)b * T;
    TBlk T0, T1;
    T0.lo = *(const int4*)(tg);
    T0.hi = *(const int4*)(tg + 4);
    {
      const int o = BS * min(1, nblk - 1);
      T1.lo = *(const int4*)(tg + o);
      T1.hi = *(const int4*)(tg + o + 4);
    }
    for (int k = 0; k < nblk; ++k) {
      const float* ldsrow = &sbuf[k & 1][lane * PITCH];
      float cv[ROWF];
#pragma unroll
      for (int i = 0; i < ROWF; ++i) cv[i] = ldsrow[i];
      if (k + 1 < nblk) {
        stage_flush(S, sbuf[(k + 1) & 1], lane);
        stage_load(S, pot, bbase, TK, BS * min(k + 2, nblk - 1), lane);
      }
      fwd_chunk(cv, T0, k, len, W, s_trans, p, Cacc, unary, binary, pt);
      T0 = T1;
      const int o = BS * min(k + 2, nblk - 1);
      T1.lo = *(const int4*)(tg + o);
      T1.hi = *(const int4*)(tg + o + 4);
    }
    const float zsum = p[0] + p[1] + p[2] + p[3] + p[4];
    const float logZ = Cacc + __logf(zsum);
    out[(size_t)B * T + b] = unary + binary - logZ;
  }
}

// ---------------------------------------------------------------------------
extern "C" void kernel_launch(void* const* d_in, const int* in_sizes, int n_in,
                              void* d_out, int out_size, void* d_ws, size_t ws_size,
                              hipStream_t stream) {
  const float* pot   = (const float*)d_in[0];
  const float* trans = (const float*)d_in[1];
  const int*   lens  = (const int*)d_in[2];
  const int*   tags  = (const int*)d_in[3];
  float* out = (float*)d_out;

  const int B = in_sizes[2];
  const int T = in_sizes[3] / B;   // 512

  uint4* bp4 = (uint4*)d_ws;       // B * 64 * 16 B = 8 MB backpointer scratch

  crf_kernel<<<2 * (B / 64), 64, 0, stream>>>(pot, trans, lens, tags, out, bp4, B, T);
}

// Round 6
// 114.986 us; speedup vs baseline: 1.4435x; 1.4435x over previous
//
#include <hip/hip_runtime.h>
#include <stdint.h>

#define KK 5
#define TT 512

// ---- cross-lane helpers (8-lane groups; 8 | 32 so groups never straddle the
// ds_swizzle 32-lane boundary) ----
template<int P>
__device__ __forceinline__ float swzf(float v) {
  return __int_as_float(__builtin_amdgcn_ds_swizzle(__float_as_int(v), P));
}
template<int P>
__device__ __forceinline__ int swzi(int v) {
  return __builtin_amdgcn_ds_swizzle(v, P);
}
// broadcast lane (group*8 + i): offset = (i<<5) | 0x18
#define BC0 0x018
#define BC1 0x038
#define BC2 0x058
#define BC3 0x078
#define BC4 0x098
// xor-butterfly within 8-lane group: offset = (m<<10) | 0x1F
#define X1 0x041F
#define X2 0x081F
#define X4 0x101F

// select among 5 statically-indexed u32 by runtime idx 0..4 (4 cndmask)
__device__ __forceinline__ uint32_t sel5u(uint32_t w0, uint32_t w1, uint32_t w2,
                                          uint32_t w3, uint32_t w4, int ct) {
  uint32_t u = w0;
  u = (ct == 1) ? w1 : u;
  u = (ct == 2) ? w2 : u;
  u = (ct == 3) ? w3 : u;
  u = (ct == 4) ? w4 : u;
  return u;
}

// load one 8-step column block: element t for t = 8k+1 .. 8k+8 (clamped)
__device__ __forceinline__ void loadCol(float (&d)[8], const float* __restrict__ colp, int k) {
  const int t0 = k * 8 + 1;
  if (k < 63) {
#pragma unroll
    for (int s = 0; s < 8; ++s) d[s] = colp[(t0 + s) * KK];
  } else {
#pragma unroll
    for (int s = 0; s < 8; ++s) d[s] = colp[min(t0 + s, TT - 1) * KK];
  }
}

// ---------------- Viterbi: 8 scan steps, bp word off-chain to LDS ----------
__device__ __forceinline__ void vit_blk(const float (&pv)[8], int k, int len,
                                        const float (&trc)[KK], float& a,
                                        float& a_fin, int g, int r, int jj,
                                        uint32_t* __restrict__ s_bits) {
  uint32_t bits = 0;
#pragma unroll
  for (int s = 0; s < 8; ++s) {
    const int t = k * 8 + s + 1;
    const float av0 = swzf<BC0>(a), av1 = swzf<BC1>(a), av2 = swzf<BC2>(a),
                av3 = swzf<BC3>(a), av4 = swzf<BC4>(a);
    const float s0 = av0 + trc[0], s1 = av1 + trc[1], s2 = av2 + trc[2],
                s3 = av3 + trc[3], s4 = av4 + trc[4];
    const float bm = fmaxf(fmaxf(fmaxf(s0, s1), fmaxf(s2, s3)), s4);
    int bi = 4;                      // first-max tie-break == jnp.argmax
    bi = (s3 == bm) ? 3 : bi;
    bi = (s2 == bm) ? 2 : bi;
    bi = (s1 == bm) ? 1 : bi;
    bi = (s0 == bm) ? 0 : bi;
    bits |= (uint32_t)bi << (3 * s);
    a = bm + pv[s];                  // no freeze: runs (bounded) past len-1
    a_fin = (t == len - 1) ? a : a_fin;   // off-chain capture
  }
  if (r < 5) s_bits[g * 321 + k * 5 + jj] = bits;
}

// ---------------- forward: 8 linear-space steps, pow2 renorm fold ----------
__device__ __forceinline__ void fwd_blk(const float (&pv)[8], int k, int len,
                                        const float (&Wc)[KK], float& p,
                                        float& Cacc, float& p_fin, float& C_fin) {
#pragma unroll
  for (int s = 0; s < 8; ++s) {
    const int t = k * 8 + s + 1;
    const float p0 = swzf<BC0>(p), p1 = swzf<BC1>(p), p2 = swzf<BC2>(p),
                p3 = swzf<BC3>(p), p4 = swzf<BC4>(p);
    float r_ = 1.0f;
    if (s == 0 && k > 0) {
      // renorm from already-broadcast values: exact power-of-2, lane-uniform
      const float m = fmaxf(fmaxf(fmaxf(p0, p1), fmaxf(p2, p3)), p4);
      const int e = ilogbf(m);
      r_ = ldexpf(1.0f, -e);
      Cacc += (float)e * 0.69314718056f;
    }
    const float E = __expf(pv[s]);
    float acc = fmaf(p1, Wc[1], p0 * Wc[0]);
    const float acc2 = fmaf(p3, Wc[3], p2 * Wc[2]);
    acc = fmaf(p4, Wc[4], acc + acc2);
    p = acc * E * r_;
    p_fin = (t == len - 1) ? p : p_fin;     // off-chain captures
    C_fin = (t == len - 1) ? Cacc : C_fin;
  }
}

// ---------------------------------------------------------------------------
// grid: 2*(B/8) blocks x 64 threads (1 wave). 8 batches/wave, 8 lanes/batch
// (5 compute tags). role via (blockIdx>>3)&1; blocks u and u+8 share batches
// and XCD. No barriers; backtrace/decode fully post-scan.
// ---------------------------------------------------------------------------
__launch_bounds__(64)
__global__ void crf_kernel(const float* __restrict__ pot,
                           const float* __restrict__ trans,
                           const int* __restrict__ lens,
                           const int* __restrict__ tags,
                           float* __restrict__ out,
                           int B, int T) {
  __shared__ uint32_t s_bits[8 * 321];    // [g][k][j] at g*321 + k*5 + j
  __shared__ uint32_t s_chosen[8 * 65];   // packed decoded tags per block
  const int lane = threadIdx.x;
  const int g = lane >> 3, r = lane & 7;
  const int jj = (r < 5) ? r : 4;
  const unsigned u = blockIdx.x;
  const int role = (u >> 3) & 1;
  const int idx = (int)((u & 7u) | ((u >> 4) << 3));
  const int b = idx * 8 + g;
  const int len = lens[b];
  const float* __restrict__ prow = pot + (size_t)b * (T * KK);
  const float* __restrict__ colp = prow + jj;

  int ml = len;
  ml = max(ml, __shfl_xor(ml, 8));
  ml = max(ml, __shfl_xor(ml, 16));
  ml = max(ml, __shfl_xor(ml, 32));
  const int nblk = (ml + 7) >> 3;

  if (role == 0) {
    // ========================= Viterbi =========================
    float trc[KK];
#pragma unroll
    for (int i = 0; i < KK; ++i) trc[i] = trans[i * KK + jj];
    float a = (r < 5) ? prow[jj] : -3.0e38f;
    float a_fin = a;                       // covers len==1

    float pA[8], pB[8], pC[8];
    loadCol(pA, colp, 0);
    loadCol(pB, colp, min(1, nblk - 1));
    loadCol(pC, colp, min(2, nblk - 1));
    int blk = 0;
    while (true) {
      vit_blk(pA, blk, len, trc, a, a_fin, g, r, jj, s_bits);
      if (++blk == nblk) break;
      loadCol(pA, colp, min(blk + 2, nblk - 1));
      vit_blk(pB, blk, len, trc, a, a_fin, g, r, jj, s_bits);
      if (++blk == nblk) break;
      loadCol(pB, colp, min(blk + 2, nblk - 1));
      vit_blk(pC, blk, len, trc, a, a_fin, g, r, jj, s_bits);
      if (++blk == nblk) break;
      loadCol(pC, colp, min(blk + 2, nblk - 1));
    }
    // final argmax (first-max) over lanes r<5
    float bm = a_fin;
    bm = fmaxf(bm, swzf<X1>(bm));
    bm = fmaxf(bm, swzf<X2>(bm));
    bm = fmaxf(bm, swzf<X4>(bm));
    int cand = (r < 5 && a_fin == bm) ? r : 7;
    cand = min(cand, swzi<X1>(cand));
    cand = min(cand, swzi<X2>(cand));
    cand = min(cand, swzi<X4>(cand));
    const int last = cand;

    // ============ post-scan backtrace: lane r==0 per group ============
    if (r == 0) {
      int tag = last;
      uint32_t acc = (uint32_t)last << (3 * ((len - 1) & 7));
      int kcur = (len - 1) >> 3;
      const uint32_t* __restrict__ bb = s_bits + g * 321;
      int kb = (len - 2) >> 3;               // len==1 -> -1, loop skipped
      // prefetch current block's 5 words
      uint32_t w0 = 0, w1 = 0, w2 = 0, w3 = 0, w4 = 0;
      if (kb >= 0) {
        w0 = bb[kb * 5 + 0]; w1 = bb[kb * 5 + 1]; w2 = bb[kb * 5 + 2];
        w3 = bb[kb * 5 + 3]; w4 = bb[kb * 5 + 4];
      }
      for (; kb >= 0; --kb) {
        // prefetch next block down while walking this one
        uint32_t n0 = 0, n1 = 0, n2 = 0, n3 = 0, n4 = 0;
        if (kb > 0) {
          n0 = bb[(kb - 1) * 5 + 0]; n1 = bb[(kb - 1) * 5 + 1];
          n2 = bb[(kb - 1) * 5 + 2]; n3 = bb[(kb - 1) * 5 + 3];
          n4 = bb[(kb - 1) * 5 + 4];
        }
#pragma unroll
        for (int s = 7; s >= 0; --s) {
          const int t = kb * 8 + s + 1;      // transition into t; position t-1
          if (t <= len - 1) {
            const uint32_t w = sel5u(w0, w1, w2, w3, w4, tag);
            const int prev = (int)((w >> (3 * s)) & 7u);
            if (kb != kcur) { s_chosen[g * 65 + kcur] = acc; acc = 0; kcur = kb; }
            acc |= (uint32_t)prev << (3 * s);
            tag = prev;
          }
        }
        w0 = n0; w1 = n1; w2 = n2; w3 = n3; w4 = n4;
      }
      s_chosen[g * 65 + kcur] = acc;
    }

    // ============ coalesced decoded write (all lanes) ============
    float* __restrict__ orow = out + (size_t)b * T;
#pragma unroll
    for (int kk = 0; kk < 8; ++kk) {
      const int k2 = kk * 8 + r;
      const uint32_t w = s_chosen[g * 65 + k2];
      const int base = k2 * 8;
      float f[8];
#pragma unroll
      for (int pI = 0; pI < 8; ++pI)
        f[pI] = (base + pI < len) ? (float)((w >> (3 * pI)) & 7u) : 0.0f;
      *(float4*)(orow + base)     = make_float4(f[0], f[1], f[2], f[3]);
      *(float4*)(orow + base + 4) = make_float4(f[4], f[5], f[6], f[7]);
    }

  } else {
    // ==================== forward + score ====================
    // issue scan prefetch first so it arrives during the score prologue
    float pA[8], pB[8], pC[8];
    loadCol(pA, colp, 0);
    loadCol(pB, colp, min(1, nblk - 1));
    loadCol(pC, colp, min(2, nblk - 1));

    const float trv = trans[min(lane, 24)];   // distributed 5x5 table
    // ---- score prologue: lane r sums t in [r*64, r*64+64) of its batch ----
    const int* __restrict__ tgrow = tags + (size_t)b * T;
    float sc = 0.0f;
    {
      const int t0 = r * 64;
      int ptag = (t0 == 0) ? 0 : tgrow[t0 - 1];
#pragma unroll 2
      for (int q = 0; q < 16; ++q) {
        const int4 tq = *(const int4*)(tgrow + t0 + q * 4);
#pragma unroll
        for (int m = 0; m < 4; ++m) {
          const int t = t0 + q * 4 + m;
          const int ct = (m == 0) ? tq.x : (m == 1) ? tq.y : (m == 2) ? tq.z : tq.w;
          const float uadd = prow[t * KK + ct];
          const float badd = __int_as_float(__builtin_amdgcn_ds_bpermute(
              (ptag * KK + ct) << 2, __float_as_int(trv)));
          const float contrib = uadd + ((t >= 1) ? badd : 0.0f);
          sc += (t < len) ? contrib : 0.0f;
          ptag = ct;
        }
      }
    }
    sc += swzf<X1>(sc);
    sc += swzf<X2>(sc);
    sc += swzf<X4>(sc);                 // group total

    // ---- forward scan (linear space, pow2 renorm fold) ----
    float Wc[KK];
#pragma unroll
    for (int i = 0; i < KK; ++i) Wc[i] = __expf(trans[i * KK + jj]);
    float p = (r < 5) ? __expf(prow[jj]) : 0.0f;
    float Cacc = 0.0f;
    float p_fin = p, C_fin = 0.0f;      // covers len==1

    int blk = 0;
    while (true) {
      fwd_blk(pA, blk, len, Wc, p, Cacc, p_fin, C_fin);
      if (++blk == nblk) break;
      loadCol(pA, colp, min(blk + 2, nblk - 1));
      fwd_blk(pB, blk, len, Wc, p, Cacc, p_fin, C_fin);
      if (++blk == nblk) break;
      loadCol(pB, colp, min(blk + 2, nblk - 1));
      fwd_blk(pC, blk, len, Wc, p, Cacc, p_fin, C_fin);
      if (++blk == nblk) break;
      loadCol(pC, colp, min(blk + 2, nblk - 1));
    }
    float ps = (r < 5) ? p_fin : 0.0f;
    ps += swzf<X1>(ps);
    ps += swzf<X2>(ps);
    ps += swzf<X4>(ps);
    const float logZ = C_fin + __logf(ps);
    if (r == 0) out[(size_t)B * T + b] = sc - logZ;
  }
}

// ---------------------------------------------------------------------------
extern "C" void kernel_launch(void* const* d_in, const int* in_sizes, int n_in,
                              void* d_out, int out_size, void* d_ws, size_t ws_size,
                              hipStream_t stream) {
  const float* pot   = (const float*)d_in[0];
  const float* trans = (const float*)d_in[1];
  const int*   lens  = (const int*)d_in[2];
  const int*   tags  = (const int*)d_in[3];
  float* out = (float*)d_out;

  const int B = in_sizes[2];
  const int T = in_sizes[3] / B;   // 512

  const int nblocks = 2 * (B / 8);  // 2048
  crf_kernel<<<nblocks, 64, 0, stream>>>(pot, trans, lens, tags, out, B, T);
}